// Round 17
// baseline (566.251 us; speedup 1.0000x reference)
//
#include <hip/hip_runtime.h>
#include <hip/hip_bf16.h>

#define B_N 128
#define T_N 2048
#define H_N 512

typedef __attribute__((ext_vector_type(8))) short bf16x8;   // 8 bf16 = 4 VGPRs
typedef __attribute__((ext_vector_type(4))) float f32x4;    // MFMA acc

union U4 { unsigned int i[4]; bf16x8 v; };

// RNE f32 -> bf16 (low 16 bits)
__device__ __forceinline__ unsigned int f2bf(float f) {
    unsigned int u = __float_as_uint(f);
    u += 0x7fffu + ((u >> 16) & 1u);
    return u >> 16;
}

// packed f32x2 -> bf16x2 (RNE), single VALU inst
__device__ __forceinline__ unsigned int cvtpk(float lo, float hi) {
    unsigned int r;
    asm("v_cvt_pk_bf16_f32 %0, %1, %2" : "=v"(r) : "v"(lo), "v"(hi));
    return r;
}

// x >= 0 always here (relu+relu)
__device__ __forceinline__ float tanh_fast(float x) {
    float e = __expf(2.f * x);
    float r = __builtin_amdgcn_rcpf(e + 1.f);
    return 1.f - 2.f * r;
}

#define FENCE asm volatile("" ::: "memory")
#define SBAR  do { FENCE; __builtin_amdgcn_s_barrier(); FENCE; } while (0)
#define VMCNT(n) asm volatile("s_waitcnt vmcnt(" #n ")" ::: "memory")
#define LGKM0    asm volatile("s_waitcnt lgkmcnt(0)" ::: "memory")
#define SCHED0   __builtin_amdgcn_sched_barrier(0)

// ---------------------------------------------------------------------------
// K2 (v3): pack w2 (512x512 f32) -> bf16 in per-wave MFMA FRAGMENT order:
// 16B chunk index t = [wc(3b) | ks(4b) | n(2b) | lane(6b)], byte off = t*16.
// Chunk content: lane's B-fragment for wave-column wc, k32-slice ks, n-frag n:
//   g = wc*64 + n*16 + (lane&15);  k = ks*32 + (lane>>4)*8 .. +8.
// k_scores waves read B frags from L2 with perfectly coalesced dwordx4
// (64 lanes x 16B = 1KB contiguous per fragment) — NO LDS for B at all.
// ---------------------------------------------------------------------------
__global__ void k_w2prep(const float* __restrict__ w2, unsigned short* __restrict__ w2p) {
    int t = blockIdx.x * 256 + threadIdx.x;      // 0..32767
    int l  = t & 63;
    int n  = (t >> 6) & 3;
    int ks = (t >> 8) & 15;
    int wc = t >> 12;
    int g  = wc * 64 + n * 16 + (l & 15);
    int k0 = ks * 32 + (l >> 4) * 8;
    const float4* s = reinterpret_cast<const float4*>(w2 + (size_t)g * H_N + k0);
    float4 f0 = s[0], f1 = s[1];
    uint4 p;
    p.x = f2bf(f0.x) | (f2bf(f0.y) << 16);
    p.y = f2bf(f0.z) | (f2bf(f0.w) << 16);
    p.z = f2bf(f1.x) | (f2bf(f1.y) << 16);
    p.w = f2bf(f1.z) | (f2bf(f1.w) << 16);
    *reinterpret_cast<uint4*>(reinterpret_cast<char*>(w2p) + (size_t)t * 16) = p;
}

// ---------------------------------------------------------------------------
// K1: q_h[b][g] = relu(query[b]·w1[g])   (f32, tiny; w1 L2-resident)
// ---------------------------------------------------------------------------
__global__ void k_qh(const float* __restrict__ query, const float* __restrict__ w1,
                     float* __restrict__ qh) {
    int b = blockIdx.x;
    int g = threadIdx.x;                          // 512 threads
    __shared__ float q[H_N];
    q[g] = query[(size_t)b * H_N + g];
    __syncthreads();
    const float4* w = reinterpret_cast<const float4*>(w1 + (size_t)g * H_N);
    float acc = 0.f;
#pragma unroll 4
    for (int i = 0; i < H_N / 4; ++i) {
        float4 wv = w[i];
        acc += q[4*i] * wv.x + q[4*i+1] * wv.y + q[4*i+2] * wv.z + q[4*i+3] * wv.w;
    }
    qh[(size_t)b * H_N + g] = fmaxf(acc, 0.f);
}

// ---------------------------------------------------------------------------
// K3 (fused): grid (16,128); each block handles TWO 64-row chunks.
//   s_t = sum_g w_out[g]*tanh(qh[b][g] + relu(key[b][t]·w2[g]))  -> w_t=exp(s_t)
//   psum[b][c] = sum_t w_t ;  partial[b][c][h] = sum_t w_t * key_bf16[t][h]
// r16 structure (confirmed): A once full-K in 64KB LDS bf16 tile; B per-wave
// fragment-packed L2->regs depth-2; ZERO-barrier K-loop; KSTEP hoist+setprio.
// r17: CROSS-CHUNK PREFETCH — chunk 1's A-loads issued right after chunk 0's
// epilogue (acc dead -> no VGPR spike); B(0/1) reissued mid-staging. All tail
// barriers are LGKM0 + raw s_barrier so the vm FIFO survives; every counted
// VMCNT audited against the FIFO incl. the partial/psum stores.
// LDS ~67.8KB -> 2 blocks/CU, 4 waves/SIMD.
// ---------------------------------------------------------------------------
__global__ __launch_bounds__(512, 4) void k_scores(
    const float* __restrict__ key, const unsigned short* __restrict__ w2p,
    const float* __restrict__ qh, const float* __restrict__ w_out,
    float* __restrict__ partial, float* __restrict__ psum)
{
    const int b    = blockIdx.y;
    const int chnk = blockIdx.x;    // 0..15 (2 chunks each)
    const int tid  = threadIdx.x;
    const int wid  = tid >> 6;      // wave's g-column wc = wid (1x8)
    const int lane = tid & 63;
    const int lrow = lane & 15;     // fragment row/col
    const int lq   = lane >> 4;     // 0..3 k-group
    const int xm   = lrow & 7;      // A-read slot XOR

    __shared__ __align__(16) char Ab[65536];     // 64 rows x 1024B bf16, swizzled slots
    __shared__ float sscore[8][64];
    __shared__ float wlds[64];

    // ---- A staging geometry: row = tid>>3, 16-f32 run col = (tid&7) ----
    const int arow = tid >> 3;
    const int acol = tid & 7;
    const int axm  = arow & 7;
    const float* asrc0 = key + ((size_t)b * T_N + chnk * 128 + arow) * H_N + acol * 16;

    // ---- B per-wave fragment base: wave wid, lane -> contiguous 16B ----
    const char* bptr = reinterpret_cast<const char*>(w2p) + wid * 65536 + lane * 16;

    float4 Ra[4], Rb[4];
    bf16x8 br0[4], br1[4];

#define ALOAD(BASE, p, R) do {                                                \
        const float4* q_ = reinterpret_cast<const float4*>((BASE) + (p) * 128); \
        R[0] = q_[0]; R[1] = q_[1]; R[2] = q_[2]; R[3] = q_[3];               \
    } while (0)

#define AWRITE(p, R) do {                                                     \
        U4 u0_, u1_;                                                          \
        u0_.i[0] = cvtpk(R[0].x, R[0].y); u0_.i[1] = cvtpk(R[0].z, R[0].w);   \
        u0_.i[2] = cvtpk(R[1].x, R[1].y); u0_.i[3] = cvtpk(R[1].z, R[1].w);   \
        u1_.i[0] = cvtpk(R[2].x, R[2].y); u1_.i[1] = cvtpk(R[2].z, R[2].w);   \
        u1_.i[2] = cvtpk(R[3].x, R[3].y); u1_.i[3] = cvtpk(R[3].z, R[3].w);   \
        *reinterpret_cast<bf16x8*>(Ab + arow * 1024 +                         \
            ((((p) * 16 + acol * 2)     ^ axm) << 4)) = u0_.v;                \
        *reinterpret_cast<bf16x8*>(Ab + arow * 1024 +                         \
            ((((p) * 16 + acol * 2 + 1) ^ axm) << 4)) = u1_.v;                \
    } while (0)

#define LOADB(sl, R) do {                                                     \
        R[0] = *reinterpret_cast<const bf16x8*>(bptr + (sl) * 4096);          \
        R[1] = *reinterpret_cast<const bf16x8*>(bptr + (sl) * 4096 + 1024);   \
        R[2] = *reinterpret_cast<const bf16x8*>(bptr + (sl) * 4096 + 2048);   \
        R[3] = *reinterpret_cast<const bf16x8*>(bptr + (sl) * 4096 + 3072);   \
    } while (0)

    f32x4 acc[4][4];

    // KSTEP: A ds_reads FIRST (latency overlaps the B wait), counted VMCNT,
    // sched fence (rule #18), prioritized MFMA cluster, then refill CUR.
#define KSTEP(ks, CUR, CNT, ISSUE) do {                                       \
        bf16x8 av_[4];                                                        \
        _Pragma("unroll")                                                     \
        for (int m_ = 0; m_ < 4; ++m_)                                        \
            av_[m_] = *reinterpret_cast<const bf16x8*>(                       \
                Ab + (m_ * 16 + lrow) * 1024 + ((((ks) * 4 + lq) ^ xm) << 4));\
        VMCNT(CNT);                                                           \
        SCHED0;                                                               \
        __builtin_amdgcn_s_setprio(1);                                        \
        _Pragma("unroll")                                                     \
        for (int m_ = 0; m_ < 4; ++m_) {                                      \
            acc[m_][0] = __builtin_amdgcn_mfma_f32_16x16x32_bf16(av_[m_], CUR[0], acc[m_][0], 0, 0, 0); \
            acc[m_][1] = __builtin_amdgcn_mfma_f32_16x16x32_bf16(av_[m_], CUR[1], acc[m_][1], 0, 0, 0); \
            acc[m_][2] = __builtin_amdgcn_mfma_f32_16x16x32_bf16(av_[m_], CUR[2], acc[m_][2], 0, 0, 0); \
            acc[m_][3] = __builtin_amdgcn_mfma_f32_16x16x32_bf16(av_[m_], CUR[3], acc[m_][3], 0, 0, 0); \
        }                                                                     \
        __builtin_amdgcn_s_setprio(0);                                        \
        if (ISSUE) LOADB((ks) + 2, CUR);                                      \
    } while (0)

    // ---- cold prologue (chunk 0): A staged, B slice 0/1 prefetched ----
    ALOAD(asrc0, 0, Ra); ALOAD(asrc0, 1, Rb);           // 8 out
    VMCNT(4);  AWRITE(0, Ra); ALOAD(asrc0, 2, Ra);      // 8 out
    VMCNT(4);  AWRITE(1, Rb); ALOAD(asrc0, 3, Rb);      // 8 out
    VMCNT(4);  AWRITE(2, Ra);
    LOADB(0, br0); LOADB(1, br1);                       // 12 out
    VMCNT(8);  AWRITE(3, Rb);                           // B0+B1 in flight
    LGKM0;
    SBAR;

#pragma unroll
    for (int jj = 0; jj < 2; ++jj) {
        const int c32 = chnk * 2 + jj;
        const float* asrcN = asrc0 + 64 * H_N;          // next chunk (jj==0 only)

#pragma unroll
        for (int m = 0; m < 4; ++m)
#pragma unroll
            for (int n = 0; n < 4; ++n) acc[m][n] = f32x4{0.f, 0.f, 0.f, 0.f};

        // ---- 16 k32-slices, ZERO barriers; vm FIFO empty at exit ----
        KSTEP(0,  br0, 4, 1); KSTEP(1,  br1, 4, 1);
        KSTEP(2,  br0, 4, 1); KSTEP(3,  br1, 4, 1);
        KSTEP(4,  br0, 4, 1); KSTEP(5,  br1, 4, 1);
        KSTEP(6,  br0, 4, 1); KSTEP(7,  br1, 4, 1);
        KSTEP(8,  br0, 4, 1); KSTEP(9,  br1, 4, 1);
        KSTEP(10, br0, 4, 1); KSTEP(11, br1, 4, 1);
        KSTEP(12, br0, 4, 1); KSTEP(13, br1, 4, 1);
        KSTEP(14, br0, 4, 0); KSTEP(15, br1, 0, 0);

        // ---- epilogue: pscore = sum_n w_out*tanh(qh + relu(acc)) ----
        float pscore[4][4] = {};        // [m][r]
#pragma unroll
        for (int n = 0; n < 4; ++n) {
            int g = wid * 64 + n * 16 + lrow;
            float wo = w_out[g];
            float qv = qh[(size_t)b * H_N + g];
#pragma unroll
            for (int m = 0; m < 4; ++m)
#pragma unroll
                for (int r = 0; r < 4; ++r) {
                    float x = qv + fmaxf(acc[m][n][r], 0.f);
                    pscore[m][r] = fmaf(wo, tanh_fast(x), pscore[m][r]);
                }
        }

        // ---- cross-chunk A prefetch (acc dead -> no VGPR spike) ----
        if (jj == 0) { ALOAD(asrcN, 0, Ra); ALOAD(asrcN, 1, Rb); }   // 8 out

        // ---- reduce over 16 frag cols (lanes), then over 8 waves via LDS ----
#pragma unroll
        for (int m = 0; m < 4; ++m)
#pragma unroll
            for (int r = 0; r < 4; ++r) {
                float v = pscore[m][r];
                v += __shfl_xor(v, 1);
                v += __shfl_xor(v, 2);
                v += __shfl_xor(v, 4);
                v += __shfl_xor(v, 8);
                if (lrow == 0) sscore[wid][m * 16 + lq * 4 + r] = v;
            }
        LGKM0; SBAR;                    // raw: keeps prefetch in flight

        // w_t = exp(s_t) (no max-sub: |s| <= Sum|w_out| ~ 18, exact shift)
        if (tid < 64) {
            float s = 0.f;
#pragma unroll
            for (int w = 0; w < 8; ++w) s += sscore[w][tid];
            wlds[tid] = __expf(s);
        }
        LGKM0; SBAR;

        // psum (wave 0): +1 store on wave 0's vm FIFO
        if (wid == 0) {
            float v = wlds[lane];
            v += __shfl_xor(v, 1);
            v += __shfl_xor(v, 2);
            v += __shfl_xor(v, 4);
            v += __shfl_xor(v, 8);
            v += __shfl_xor(v, 16);
            v += __shfl_xor(v, 32);
            if (lane == 0) psum[b * 32 + c32] = v;
        }

        // PV from LDS A tile (b128; swizzle identity: h-block == lane)
        float pv[8] = {};
#pragma unroll
        for (int i = 0; i < 8; ++i) {
            int t = wid * 8 + i;
            bf16x8 kv = *reinterpret_cast<const bf16x8*>(
                Ab + t * 1024 + ((lane ^ i) << 4));
            float wt = wlds[t];
#pragma unroll
            for (int e = 0; e < 8; ++e)
                pv[e] = fmaf(wt, __uint_as_float((unsigned)(unsigned short)kv[e] << 16), pv[e]);
        }
        LGKM0; SBAR;                    // all PV reads of Ab done; safe to alias

        // cross-wave PV reduce via LDS (aliases Ab): pvred[w][h]
        float* pvred = reinterpret_cast<float*>(Ab);
        {
            float4 lo, hi;
            lo.x = pv[0]; lo.y = pv[1]; lo.z = pv[2]; lo.w = pv[3];
            hi.x = pv[4]; hi.y = pv[5]; hi.z = pv[6]; hi.w = pv[7];
            *reinterpret_cast<float4*>(pvred + wid * 512 + lane * 8)     = lo;
            *reinterpret_cast<float4*>(pvred + wid * 512 + lane * 8 + 4) = hi;
        }
        LGKM0; SBAR;
        {
            float s = 0.f;
#pragma unroll
            for (int w = 0; w < 8; ++w) s += pvred[w * 512 + tid];
            partial[((size_t)(b * 32 + c32)) * H_N + tid] = s;   // +1 store
        }

        if (jj == 0) {
            // Ab free only after every wave's pvred reads complete
            LGKM0; SBAR;
            // vm FIFO (oldest->newest): Ra(4), Rb(4), [psum st], partial st
            VMCNT(5);                    // Ra done (wave0 drains 1 extra)
            AWRITE(0, Ra); ALOAD(asrcN, 2, Ra);
            VMCNT(5);                    // Rb done
            AWRITE(1, Rb); ALOAD(asrcN, 3, Rb);
            LOADB(0, br0); LOADB(1, br1);
            // FIFO: st(<=2), Ra2(4), Rb3(4), B(8)
            VMCNT(12);                   // stores + Ra2 drained
            AWRITE(2, Ra);
            VMCNT(8);                    // Rb3 drained; B0+B1 stay in flight
            AWRITE(3, Rb);
            LGKM0;
            SBAR;                        // chunk-1 A tile ready; B in flight
        }
    }

#undef ALOAD
#undef AWRITE
#undef LOADB
#undef KSTEP
}

// ---------------------------------------------------------------------------
// K4: out[b][h] = (sum_c partial[b][c][h]) / (sum_c psum[b][c])
// ---------------------------------------------------------------------------
__global__ void k_out(const float* __restrict__ partial, const float* __restrict__ psum,
                      float* __restrict__ out) {
    int idx = blockIdx.x * 256 + threadIdx.x;   // 65536 outputs
    int b = idx >> 9, h = idx & 511;
    float s = 0.f, d = 0.f;
#pragma unroll
    for (int c = 0; c < 32; ++c) {
        s += partial[((size_t)(b * 32 + c)) * H_N + h];
        d += psum[b * 32 + c];
    }
    out[idx] = s / d;
}

extern "C" void kernel_launch(void* const* d_in, const int* in_sizes, int n_in,
                              void* d_out, int out_size, void* d_ws, size_t ws_size,
                              hipStream_t stream) {
    const float* query = (const float*)d_in[0];
    const float* key   = (const float*)d_in[1];
    const float* w1    = (const float*)d_in[2];
    const float* w2    = (const float*)d_in[3];
    const float* w_out = (const float*)d_in[4];
    float* out = (float*)d_out;

    char* ws = (char*)d_ws;
    unsigned short* w2p = (unsigned short*)(ws);             // 512 KB
    float* qh      = (float*)(ws + 524288);                  // 256 KB
    float* partial = (float*)(ws + 1048576);                 // 8 MB (128*32*512*4)
    float* psum    = (float*)(ws + 9437184);                 // 16 KB

    hipLaunchKernelGGL(k_w2prep, dim3(128),     dim3(256), 0, stream, w2, w2p);
    hipLaunchKernelGGL(k_qh,     dim3(128),     dim3(512), 0, stream, query, w1, qh);
    hipLaunchKernelGGL(k_scores, dim3(16, 128), dim3(512), 0, stream,
                       key, w2p, qh, w_out, partial, psum);
    hipLaunchKernelGGL(k_out,    dim3(256),     dim3(256), 0, stream, partial, psum, out);
}

// Round 18
// 238.957 us; speedup vs baseline: 2.3697x; 2.3697x over previous
//
#include <hip/hip_runtime.h>
#include <hip/hip_bf16.h>

#define B_N 128
#define T_N 2048
#define H_N 512

typedef __attribute__((ext_vector_type(8))) short bf16x8;   // 8 bf16 = 4 VGPRs
typedef __attribute__((ext_vector_type(4))) float f32x4;    // MFMA acc

union U4 { unsigned int i[4]; bf16x8 v; };

// RNE f32 -> bf16 (low 16 bits)
__device__ __forceinline__ unsigned int f2bf(float f) {
    unsigned int u = __float_as_uint(f);
    u += 0x7fffu + ((u >> 16) & 1u);
    return u >> 16;
}

// packed f32x2 -> bf16x2 (RNE), single VALU inst
__device__ __forceinline__ unsigned int cvtpk(float lo, float hi) {
    unsigned int r;
    asm("v_cvt_pk_bf16_f32 %0, %1, %2" : "=v"(r) : "v"(lo), "v"(hi));
    return r;
}

// x >= 0 always here (relu+relu)
__device__ __forceinline__ float tanh_fast(float x) {
    float e = __expf(2.f * x);
    float r = __builtin_amdgcn_rcpf(e + 1.f);
    return 1.f - 2.f * r;
}

#define FENCE asm volatile("" ::: "memory")
#define SBAR  do { FENCE; __builtin_amdgcn_s_barrier(); FENCE; } while (0)
#define VMCNT(n) asm volatile("s_waitcnt vmcnt(" #n ")" ::: "memory")
#define LGKM0    asm volatile("s_waitcnt lgkmcnt(0)" ::: "memory")
#define SCHED0   __builtin_amdgcn_sched_barrier(0)

// ---------------------------------------------------------------------------
// K2 (v3): pack w2 (512x512 f32) -> bf16 in per-wave MFMA FRAGMENT order:
// 16B chunk index t = [wc(3b) | ks(4b) | n(2b) | lane(6b)], byte off = t*16.
// Chunk content: lane's B-fragment for wave-column wc, k32-slice ks, n-frag n:
//   g = wc*64 + n*16 + (lane&15);  k = ks*32 + (lane>>4)*8 .. +8.
// k_scores waves read B frags from L2 with perfectly coalesced dwordx4
// (64 lanes x 16B = 1KB contiguous per fragment) — NO LDS for B at all.
// ---------------------------------------------------------------------------
__global__ void k_w2prep(const float* __restrict__ w2, unsigned short* __restrict__ w2p) {
    int t = blockIdx.x * 256 + threadIdx.x;      // 0..32767
    int l  = t & 63;
    int n  = (t >> 6) & 3;
    int ks = (t >> 8) & 15;
    int wc = t >> 12;
    int g  = wc * 64 + n * 16 + (l & 15);
    int k0 = ks * 32 + (l >> 4) * 8;
    const float4* s = reinterpret_cast<const float4*>(w2 + (size_t)g * H_N + k0);
    float4 f0 = s[0], f1 = s[1];
    uint4 p;
    p.x = f2bf(f0.x) | (f2bf(f0.y) << 16);
    p.y = f2bf(f0.z) | (f2bf(f0.w) << 16);
    p.z = f2bf(f1.x) | (f2bf(f1.y) << 16);
    p.w = f2bf(f1.z) | (f2bf(f1.w) << 16);
    *reinterpret_cast<uint4*>(reinterpret_cast<char*>(w2p) + (size_t)t * 16) = p;
}

// ---------------------------------------------------------------------------
// K1: q_h[b][g] = relu(query[b]·w1[g])   (f32, tiny; w1 L2-resident)
// ---------------------------------------------------------------------------
__global__ void k_qh(const float* __restrict__ query, const float* __restrict__ w1,
                     float* __restrict__ qh) {
    int b = blockIdx.x;
    int g = threadIdx.x;                          // 512 threads
    __shared__ float q[H_N];
    q[g] = query[(size_t)b * H_N + g];
    __syncthreads();
    const float4* w = reinterpret_cast<const float4*>(w1 + (size_t)g * H_N);
    float acc = 0.f;
#pragma unroll 4
    for (int i = 0; i < H_N / 4; ++i) {
        float4 wv = w[i];
        acc += q[4*i] * wv.x + q[4*i+1] * wv.y + q[4*i+2] * wv.z + q[4*i+3] * wv.w;
    }
    qh[(size_t)b * H_N + g] = fmaxf(acc, 0.f);
}

// ---------------------------------------------------------------------------
// K3 (fused): per block of 64 t-rows (grid 32 x 128):
//   s_t = sum_g w_out[g]*tanh(qh[b][g] + relu(key[b][t]·w2[g]))  -> w_t=exp(s_t)
//   psum[b][c] = sum_t w_t ;  partial[b][c][h] = sum_t w_t * key_bf16[t][h]
// r14 structure (confirmed): A staged once full-K into 64KB LDS bf16 tile;
// B per-wave fragment-packed, loaded L2->regs depth-2; ZERO-barrier K-loop.
// r16 micro-fixes (confirmed +13us): KSTEP A-hoist before the B VMCNT,
// sched_barrier(0) after the wait, s_setprio around the MFMA cluster,
// b128 PV tail + cross-wave LDS reduce.
// [r17 ERRATA]: cross-chunk prefetch (2 chunks/block, reg-sets live across
// the tail) collapsed regalloc to 64 VGPR + 827MB scratch spill — REVERTED.
// LDS ~67.8KB -> 2 blocks/CU, 4 waves/SIMD. VGPR <= 128 (B depth stays 2).
// ---------------------------------------------------------------------------
__global__ __launch_bounds__(512, 4) void k_scores(
    const float* __restrict__ key, const unsigned short* __restrict__ w2p,
    const float* __restrict__ qh, const float* __restrict__ w_out,
    float* __restrict__ partial, float* __restrict__ psum)
{
    const int b    = blockIdx.y;
    const int chnk = blockIdx.x;
    const int t0   = chnk * 64;
    const int tid  = threadIdx.x;
    const int wid  = tid >> 6;      // wave's g-column wc = wid (1x8)
    const int lane = tid & 63;
    const int lrow = lane & 15;     // fragment row/col
    const int lq   = lane >> 4;     // 0..3 k-group
    const int xm   = lrow & 7;      // A-read slot XOR

    __shared__ __align__(16) char Ab[65536];     // 64 rows x 1024B bf16, swizzled slots
    __shared__ float sscore[8][64];
    __shared__ float wlds[64];

    // ---- A staging geometry: row = tid>>3, 16-f32 run col = (tid&7) ----
    const int arow = tid >> 3;
    const int acol = tid & 7;
    const int axm  = arow & 7;
    const float* asrc = key + ((size_t)b * T_N + t0 + arow) * H_N + acol * 16;

    // ---- B per-wave fragment base: wave wid, lane -> contiguous 16B ----
    const char* bptr = reinterpret_cast<const char*>(w2p) + wid * 65536 + lane * 16;

    float4 Ra[4], Rb[4];
    bf16x8 br0[4], br1[4];

#define ALOAD(p, R) do {                                                      \
        const float4* q_ = reinterpret_cast<const float4*>(asrc + (p) * 128); \
        R[0] = q_[0]; R[1] = q_[1]; R[2] = q_[2]; R[3] = q_[3];               \
    } while (0)

#define AWRITE(p, R) do {                                                     \
        U4 u0_, u1_;                                                          \
        u0_.i[0] = cvtpk(R[0].x, R[0].y); u0_.i[1] = cvtpk(R[0].z, R[0].w);   \
        u0_.i[2] = cvtpk(R[1].x, R[1].y); u0_.i[3] = cvtpk(R[1].z, R[1].w);   \
        u1_.i[0] = cvtpk(R[2].x, R[2].y); u1_.i[1] = cvtpk(R[2].z, R[2].w);   \
        u1_.i[2] = cvtpk(R[3].x, R[3].y); u1_.i[3] = cvtpk(R[3].z, R[3].w);   \
        *reinterpret_cast<bf16x8*>(Ab + arow * 1024 +                         \
            ((((p) * 16 + acol * 2)     ^ axm) << 4)) = u0_.v;                \
        *reinterpret_cast<bf16x8*>(Ab + arow * 1024 +                         \
            ((((p) * 16 + acol * 2 + 1) ^ axm) << 4)) = u1_.v;                \
    } while (0)

#define LOADB(sl, R) do {                                                     \
        R[0] = *reinterpret_cast<const bf16x8*>(bptr + (sl) * 4096);          \
        R[1] = *reinterpret_cast<const bf16x8*>(bptr + (sl) * 4096 + 1024);   \
        R[2] = *reinterpret_cast<const bf16x8*>(bptr + (sl) * 4096 + 2048);   \
        R[3] = *reinterpret_cast<const bf16x8*>(bptr + (sl) * 4096 + 3072);   \
    } while (0)

    f32x4 acc[4][4];

    // KSTEP: A ds_reads FIRST (latency overlaps the B wait), counted VMCNT,
    // sched fence (rule #18), prioritized MFMA cluster, then refill CUR.
#define KSTEP(ks, CUR, CNT, ISSUE) do {                                       \
        bf16x8 av_[4];                                                        \
        _Pragma("unroll")                                                     \
        for (int m_ = 0; m_ < 4; ++m_)                                        \
            av_[m_] = *reinterpret_cast<const bf16x8*>(                       \
                Ab + (m_ * 16 + lrow) * 1024 + ((((ks) * 4 + lq) ^ xm) << 4));\
        VMCNT(CNT);                                                           \
        SCHED0;                                                               \
        __builtin_amdgcn_s_setprio(1);                                        \
        _Pragma("unroll")                                                     \
        for (int m_ = 0; m_ < 4; ++m_) {                                      \
            acc[m_][0] = __builtin_amdgcn_mfma_f32_16x16x32_bf16(av_[m_], CUR[0], acc[m_][0], 0, 0, 0); \
            acc[m_][1] = __builtin_amdgcn_mfma_f32_16x16x32_bf16(av_[m_], CUR[1], acc[m_][1], 0, 0, 0); \
            acc[m_][2] = __builtin_amdgcn_mfma_f32_16x16x32_bf16(av_[m_], CUR[2], acc[m_][2], 0, 0, 0); \
            acc[m_][3] = __builtin_amdgcn_mfma_f32_16x16x32_bf16(av_[m_], CUR[3], acc[m_][3], 0, 0, 0); \
        }                                                                     \
        __builtin_amdgcn_s_setprio(0);                                        \
        if (ISSUE) LOADB((ks) + 2, CUR);                                      \
    } while (0)

    // ---- A staging (pipelined, 2 reg sets) + B slice 0/1 prefetch ----
    ALOAD(0, Ra); ALOAD(1, Rb);               // 8 out
    VMCNT(4);  AWRITE(0, Ra); ALOAD(2, Ra);   // 8 out
    VMCNT(4);  AWRITE(1, Rb); ALOAD(3, Rb);   // 8 out
    VMCNT(4);  AWRITE(2, Ra);
    LOADB(0, br0); LOADB(1, br1);             // 12 out
    VMCNT(8);  AWRITE(3, Rb);                 // A all written; B0+B1 in flight
    LGKM0;                                    // this wave's ds_writes complete
    SBAR;                                     // raw barrier: B prefetch survives

#pragma unroll
    for (int m = 0; m < 4; ++m)
#pragma unroll
        for (int n = 0; n < 4; ++n) acc[m][n] = f32x4{0.f, 0.f, 0.f, 0.f};

    // ---- 16 k32-slices, ZERO barriers ----
    KSTEP(0,  br0, 4, 1); KSTEP(1,  br1, 4, 1);
    KSTEP(2,  br0, 4, 1); KSTEP(3,  br1, 4, 1);
    KSTEP(4,  br0, 4, 1); KSTEP(5,  br1, 4, 1);
    KSTEP(6,  br0, 4, 1); KSTEP(7,  br1, 4, 1);
    KSTEP(8,  br0, 4, 1); KSTEP(9,  br1, 4, 1);
    KSTEP(10, br0, 4, 1); KSTEP(11, br1, 4, 1);
    KSTEP(12, br0, 4, 1); KSTEP(13, br1, 4, 1);
    KSTEP(14, br0, 4, 0); KSTEP(15, br1, 0, 0);

    // ---- epilogue: pscore = sum_n w_out*tanh(qh + relu(acc)) ----
    float pscore[4][4] = {};        // [m][r]
#pragma unroll
    for (int n = 0; n < 4; ++n) {
        int g = wid * 64 + n * 16 + lrow;
        float wo = w_out[g];
        float qv = qh[(size_t)b * H_N + g];
#pragma unroll
        for (int m = 0; m < 4; ++m)
#pragma unroll
            for (int r = 0; r < 4; ++r) {
                float x = qv + fmaxf(acc[m][n][r], 0.f);
                pscore[m][r] = fmaf(wo, tanh_fast(x), pscore[m][r]);
            }
    }

    // ---- reduce over 16 frag cols (lanes), then over 8 waves via LDS ----
#pragma unroll
    for (int m = 0; m < 4; ++m)
#pragma unroll
        for (int r = 0; r < 4; ++r) {
            float v = pscore[m][r];
            v += __shfl_xor(v, 1);
            v += __shfl_xor(v, 2);
            v += __shfl_xor(v, 4);
            v += __shfl_xor(v, 8);
            if (lrow == 0) sscore[wid][m * 16 + lq * 4 + r] = v;
        }
    __syncthreads();

    // ---- w_t = exp(s_t) (no max-sub: |s| <= Sum|w_out| ~ 18, exact shift) ----
    if (tid < 64) {
        float s = 0.f;
#pragma unroll
        for (int w = 0; w < 8; ++w) s += sscore[w][tid];
        wlds[tid] = __expf(s);
    }
    __syncthreads();

    // ---- psum (wave 0, overlaps PV) ----
    if (wid == 0) {
        float v = wlds[lane];
        v += __shfl_xor(v, 1);
        v += __shfl_xor(v, 2);
        v += __shfl_xor(v, 4);
        v += __shfl_xor(v, 8);
        v += __shfl_xor(v, 16);
        v += __shfl_xor(v, 32);
        if (lane == 0) psum[b * 32 + chnk] = v;
    }

    // ---- PV from LDS A tile, b128 reads: wave wid covers t in [8wid,+8);
    // swizzle identity: slot = lane^(t&7) holds h-block == lane for all t ----
    float pv[8] = {};
#pragma unroll
    for (int i = 0; i < 8; ++i) {
        int t = wid * 8 + i;
        bf16x8 kv = *reinterpret_cast<const bf16x8*>(
            Ab + t * 1024 + ((lane ^ i) << 4));
        float wt = wlds[t];
#pragma unroll
        for (int e = 0; e < 8; ++e)
            pv[e] = fmaf(wt, __uint_as_float((unsigned)(unsigned short)kv[e] << 16), pv[e]);
    }
    __syncthreads();              // all PV reads of Ab done; safe to alias

    // ---- cross-wave PV reduce via LDS (aliases Ab): pvred[w][h] ----
    float* pvred = reinterpret_cast<float*>(Ab);
    {
        float4 lo, hi;
        lo.x = pv[0]; lo.y = pv[1]; lo.z = pv[2]; lo.w = pv[3];
        hi.x = pv[4]; hi.y = pv[5]; hi.z = pv[6]; hi.w = pv[7];
        *reinterpret_cast<float4*>(pvred + wid * 512 + lane * 8)     = lo;
        *reinterpret_cast<float4*>(pvred + wid * 512 + lane * 8 + 4) = hi;
    }
    __syncthreads();
    {
        float s = 0.f;
#pragma unroll
        for (int w = 0; w < 8; ++w) s += pvred[w * 512 + tid];
        partial[((size_t)(b * 32 + chnk)) * H_N + tid] = s;
    }

#undef ALOAD
#undef AWRITE
#undef LOADB
#undef KSTEP
}

// ---------------------------------------------------------------------------
// K4: out[b][h] = (sum_c partial[b][c][h]) / (sum_c psum[b][c])
// ---------------------------------------------------------------------------
__global__ void k_out(const float* __restrict__ partial, const float* __restrict__ psum,
                      float* __restrict__ out) {
    int idx = blockIdx.x * 256 + threadIdx.x;   // 65536 outputs
    int b = idx >> 9, h = idx & 511;
    float s = 0.f, d = 0.f;
#pragma unroll
    for (int c = 0; c < 32; ++c) {
        s += partial[((size_t)(b * 32 + c)) * H_N + h];
        d += psum[b * 32 + c];
    }
    out[idx] = s / d;
}

extern "C" void kernel_launch(void* const* d_in, const int* in_sizes, int n_in,
                              void* d_out, int out_size, void* d_ws, size_t ws_size,
                              hipStream_t stream) {
    const float* query = (const float*)d_in[0];
    const float* key   = (const float*)d_in[1];
    const float* w1    = (const float*)d_in[2];
    const float* w2    = (const float*)d_in[3];
    const float* w_out = (const float*)d_in[4];
    float* out = (float*)d_out;

    char* ws = (char*)d_ws;
    unsigned short* w2p = (unsigned short*)(ws);             // 512 KB
    float* qh      = (float*)(ws + 524288);                  // 256 KB
    float* partial = (float*)(ws + 1048576);                 // 8 MB (128*32*512*4)
    float* psum    = (float*)(ws + 9437184);                 // 16 KB

    hipLaunchKernelGGL(k_w2prep, dim3(128),     dim3(256), 0, stream, w2, w2p);
    hipLaunchKernelGGL(k_qh,     dim3(128),     dim3(512), 0, stream, query, w1, qh);
    hipLaunchKernelGGL(k_scores, dim3(32, 128), dim3(512), 0, stream,
                       key, w2p, qh, w_out, partial, psum);
    hipLaunchKernelGGL(k_out,    dim3(256),     dim3(256), 0, stream, partial, psum, out);
}